// Round 2
// baseline (217.484 us; speedup 1.0000x reference)
//
#include <hip/hip_runtime.h>
#include <hip/hip_bf16.h>
#include <math.h>

#define DEV __device__ __forceinline__

typedef float f32x4 __attribute__((ext_vector_type(4)));
typedef __bf16 b16x8 __attribute__((ext_vector_type(8)));
typedef unsigned short ushort_t;
typedef ushort_t u16x8 __attribute__((ext_vector_type(8)));

// ---- constants for this problem ----
#define BATCH 2
#define SEQ 2048
#define DMODEL 1024
#define NHEAD 16
#define HDIM 64
#define MROWS (BATCH * SEQ)          // 4096

// ws layout (in ushort elements)
#define OFF_XB   ((size_t)0)                       // [4096,1024]
#define OFF_WB   ((size_t)4 * 1024 * 1024)         // [3][1024,1024] wq,wk,wv
#define OFF_WOB  ((size_t)7 * 1024 * 1024)         // [1024,1024]
#define OFF_QKV  ((size_t)8 * 1024 * 1024)         // [3][2,16,2048,64]
#define OFF_OB   ((size_t)20 * 1024 * 1024)        // [2,2048,16,64] == [4096,1024]

DEV ushort_t f2bf(float f) {
    union { float f; unsigned u; } v; v.f = f;
    unsigned r = v.u + 0x7fffu + ((v.u >> 16) & 1u);
    return (ushort_t)(r >> 16);
}

DEV f32x4 mfma16(u16x8 a, u16x8 b, f32x4 c) {
    return __builtin_amdgcn_mfma_f32_16x16x32_bf16(
        __builtin_bit_cast(b16x8, a), __builtin_bit_cast(b16x8, b), c, 0, 0, 0);
}

DEV void gload_lds16(const ushort_t* g, ushort_t* l) {
    __builtin_amdgcn_global_load_lds(
        (const __attribute__((address_space(1))) unsigned int*)g,
        (__attribute__((address_space(3))) unsigned int*)l, 16, 0, 0);
}

// ---------------- convert f32 -> bf16 ----------------
__global__ __launch_bounds__(256) void convert5(
    const float* __restrict__ x, const float* __restrict__ wq,
    const float* __restrict__ wk, const float* __restrict__ wv,
    const float* __restrict__ wo,
    ushort_t* __restrict__ xb, ushort_t* __restrict__ wb, ushort_t* __restrict__ wob)
{
    const int ai = blockIdx.y;
    const float* src; ushort_t* dst; int n;
    if (ai == 0)      { src = x;  dst = xb;                 n = MROWS * DMODEL; }
    else if (ai == 1) { src = wq; dst = wb;                 n = DMODEL * DMODEL; }
    else if (ai == 2) { src = wk; dst = wb + 1024 * 1024;   n = DMODEL * DMODEL; }
    else if (ai == 3) { src = wv; dst = wb + 2 * 1024 * 1024; n = DMODEL * DMODEL; }
    else              { src = wo; dst = wob;                n = DMODEL * DMODEL; }
    int idx = (blockIdx.x * 256 + threadIdx.x) * 4;
    int stride = gridDim.x * 256 * 4;
    for (int i = idx; i < n; i += stride) {
        float4 f = *(const float4*)(src + i);
        ushort4 u;
        u.x = f2bf(f.x); u.y = f2bf(f.y); u.z = f2bf(f.z); u.w = f2bf(f.w);
        *(ushort4*)(dst + i) = u;
    }
}

// ---------------- NT GEMM: Y[m,n] = sum_k A[m,k] * W[n,k] (+bias) ----------------
// MODE 0: QKV projection epilogue -> bf16 [B,H,S,Hd] per matrix (blockIdx.z selects),
//         Q scaled by 1/8.
// MODE 1: output projection -> f32 d_out [4096,1024] + bias.
template<int MODE>
__global__ __launch_bounds__(256) void gemm_nt(
    const ushort_t* __restrict__ A,   // [4096,1024]
    const ushort_t* __restrict__ W,   // MODE0: [3][1024,1024]  MODE1: [1024,1024]
    const float* __restrict__ b0, const float* __restrict__ b1, const float* __restrict__ b2,
    ushort_t* __restrict__ obf,       // MODE0 dest base
    float* __restrict__ of32)         // MODE1 dest
{
    __shared__ __attribute__((aligned(16))) ushort_t ldsA[128 * 32];
    __shared__ __attribute__((aligned(16))) ushort_t ldsB[128 * 32];

    const int t = threadIdx.x;
    const int m0 = blockIdx.x * 128;
    const int n0 = blockIdx.y * 128;
    const int mat = blockIdx.z;
    const ushort_t* Wm = W + (size_t)mat * (1024 * 1024);
    const float* bias = (mat == 0) ? b0 : (mat == 1 ? b1 : b2);

    const int lane = t & 63, wave = t >> 6;
    const int wr = (wave >> 1) * 64, wc = (wave & 1) * 64;
    const int lr = lane & 15, lk = (lane >> 4) * 8;

    f32x4 acc[4][4] = {};

    for (int k0 = 0; k0 < DMODEL; k0 += 32) {
#pragma unroll
        for (int i = 0; i < 2; ++i) {
            int e = (i * 256 + t) * 8;
            int row = e >> 5, col = e & 31;
            gload_lds16(A  + (size_t)(m0 + row) * DMODEL + k0 + col, &ldsA[e]);
            gload_lds16(Wm + (size_t)(n0 + row) * DMODEL + k0 + col, &ldsB[e]);
        }
        __syncthreads();
        u16x8 av[4], bv[4];
#pragma unroll
        for (int i = 0; i < 4; ++i) av[i] = *(const u16x8*)&ldsA[(wr + i * 16 + lr) * 32 + lk];
#pragma unroll
        for (int i = 0; i < 4; ++i) bv[i] = *(const u16x8*)&ldsB[(wc + i * 16 + lr) * 32 + lk];
#pragma unroll
        for (int m = 0; m < 4; ++m)
#pragma unroll
            for (int n = 0; n < 4; ++n)
                acc[m][n] = mfma16(av[m], bv[n], acc[m][n]);
        __syncthreads();
    }

    const int lgr = (lane >> 4) * 4;
    if (MODE == 0) {
        ushort_t* dst = obf + (size_t)mat * ((size_t)MROWS * DMODEL);
        const float qscale = (mat == 0) ? 0.125f : 1.0f;
#pragma unroll
        for (int m = 0; m < 4; ++m) {
            int row = m0 + wr + m * 16 + lgr;
#pragma unroll
            for (int n = 0; n < 4; ++n) {
                int col = n0 + wc + n * 16 + lr;
                float bcol = bias[col];
                int h = col >> 6, hd = col & 63;
#pragma unroll
                for (int r = 0; r < 4; ++r) {
                    int rr = row + r;
                    int bb = rr >> 11, s = rr & 2047;
                    float v = (acc[m][n][r] + bcol) * qscale;
                    dst[(((size_t)bb * NHEAD + h) * SEQ + s) * HDIM + hd] = f2bf(v);
                }
            }
        }
    } else {
#pragma unroll
        for (int m = 0; m < 4; ++m) {
            int row = m0 + wr + m * 16 + lgr;
#pragma unroll
            for (int n = 0; n < 4; ++n) {
                int col = n0 + wc + n * 16 + lr;
                float bcol = b0[col];
#pragma unroll
                for (int r = 0; r < 4; ++r)
                    of32[(size_t)(row + r) * DMODEL + col] = acc[m][n][r] + bcol;
            }
        }
    }
}

// ---------------- flash attention ----------------
// block: (q-tile of 64 rows, head, batch). 4 waves, each owns 16 q-rows.
// Q pre-scaled by 1/sqrt(Hd) in the projection.
__global__ __launch_bounds__(256) void attn(
    const ushort_t* __restrict__ Q, const ushort_t* __restrict__ K,
    const ushort_t* __restrict__ V, ushort_t* __restrict__ O)
{
    __shared__ __attribute__((aligned(16))) ushort_t kt[64 * 72];      // [kv][hd] padded
    __shared__ __attribute__((aligned(16))) ushort_t vt[64 * 72];      // [hd][kv] padded (transposed)
    __shared__ __attribute__((aligned(16))) ushort_t pt[4][16 * 72];   // per-wave P [qrow][kv]

    const int t = threadIdx.x, lane = t & 63, wave = t >> 6;
    const int q0 = blockIdx.x * 64;
    const int h = blockIdx.y, b = blockIdx.z;
    const size_t base = ((size_t)(b * NHEAD + h)) * (SEQ * HDIM);
    const ushort_t* Qh = Q + base;
    const ushort_t* Kh = K + base;
    const ushort_t* Vh = V + base;

    const int lr = lane & 15, lg = lane >> 4, lk = lg * 8;

    u16x8 qf[2];
    {
        const ushort_t* qrow = Qh + (size_t)(q0 + wave * 16 + lr) * HDIM + lk;
        qf[0] = *(const u16x8*)(qrow);
        qf[1] = *(const u16x8*)(qrow + 32);
    }

    f32x4 oacc[4] = {};
    float mrow[4] = { -1e30f, -1e30f, -1e30f, -1e30f };
    float lrow[4] = { 0.f, 0.f, 0.f, 0.f };

    const int srow = t >> 2;           // staging row 0..63
    const int sc0 = (t & 3) * 16;      // staging col base

    for (int t0 = 0; t0 < SEQ; t0 += 64) {
        // ---- stage K (row-major, padded) and V^T (transposed, padded) ----
        {
            const ushort_t* kr = Kh + (size_t)(t0 + srow) * HDIM + sc0;
            u16x8 kv0 = *(const u16x8*)kr;
            u16x8 kv1 = *(const u16x8*)(kr + 8);
            *(u16x8*)&kt[srow * 72 + sc0]     = kv0;
            *(u16x8*)&kt[srow * 72 + sc0 + 8] = kv1;
            const ushort_t* vr = Vh + (size_t)(t0 + srow) * HDIM + sc0;
            u16x8 vv0 = *(const u16x8*)vr;
            u16x8 vv1 = *(const u16x8*)(vr + 8);
#pragma unroll
            for (int j = 0; j < 8; ++j) vt[(sc0 + j) * 72 + srow]     = (ushort_t)vv0[j];
#pragma unroll
            for (int j = 0; j < 8; ++j) vt[(sc0 + 8 + j) * 72 + srow] = (ushort_t)vv1[j];
        }
        __syncthreads();

        // ---- S = Q K^T  (rows: q, cols: kv) ----
        f32x4 s[4] = {};
#pragma unroll
        for (int n = 0; n < 4; ++n) {
#pragma unroll
            for (int kk = 0; kk < 2; ++kk) {
                u16x8 bfrag = *(const u16x8*)&kt[(n * 16 + lr) * 72 + kk * 32 + lk];
                s[n] = mfma16(qf[kk], bfrag, s[n]);
            }
        }

        // ---- online softmax (rows lg*4+r, reduce across 16 lanes) ----
        float tmax[4];
#pragma unroll
        for (int r = 0; r < 4; ++r)
            tmax[r] = fmaxf(fmaxf(s[0][r], s[1][r]), fmaxf(s[2][r], s[3][r]));
#pragma unroll
        for (int off = 1; off < 16; off <<= 1)
#pragma unroll
            for (int r = 0; r < 4; ++r)
                tmax[r] = fmaxf(tmax[r], __shfl_xor(tmax[r], off));

        float alpha[4], psum[4];
#pragma unroll
        for (int r = 0; r < 4; ++r) {
            float mnew = fmaxf(mrow[r], tmax[r]);
            alpha[r] = __expf(mrow[r] - mnew);
            mrow[r] = mnew;
            psum[r] = 0.f;
        }
        ushort_t* ptw = pt[wave];
#pragma unroll
        for (int n = 0; n < 4; ++n)
#pragma unroll
            for (int r = 0; r < 4; ++r) {
                float p = __expf(s[n][r] - mrow[r]);
                psum[r] += p;
                ptw[(lg * 4 + r) * 72 + n * 16 + lr] = f2bf(p);
            }
#pragma unroll
        for (int off = 1; off < 16; off <<= 1)
#pragma unroll
            for (int r = 0; r < 4; ++r)
                psum[r] += __shfl_xor(psum[r], off);
#pragma unroll
        for (int r = 0; r < 4; ++r)
            lrow[r] = lrow[r] * alpha[r] + psum[r];
#pragma unroll
        for (int n = 0; n < 4; ++n)
#pragma unroll
            for (int r = 0; r < 4; ++r)
                oacc[n][r] *= alpha[r];
        __syncthreads();   // P writes visible before PV reads

        // ---- O += P V ----
#pragma unroll
        for (int n = 0; n < 4; ++n)
#pragma unroll
            for (int kk = 0; kk < 2; ++kk) {
                u16x8 pa = *(const u16x8*)&ptw[lr * 72 + kk * 32 + lk];
                u16x8 vb = *(const u16x8*)&vt[(n * 16 + lr) * 72 + kk * 32 + lk];
                oacc[n] = mfma16(pa, vb, oacc[n]);
            }
        __syncthreads();   // before next tile overwrites kt/vt
    }

    // ---- epilogue: O[b, s, h*64+hd] bf16 ----
#pragma unroll
    for (int r = 0; r < 4; ++r) {
        float inv = 1.0f / lrow[r];
        int sg = q0 + wave * 16 + lg * 4 + r;
        size_t obase = ((size_t)(b * SEQ + sg)) * DMODEL + h * HDIM;
#pragma unroll
        for (int n = 0; n < 4; ++n)
            O[obase + n * 16 + lr] = f2bf(oacc[n][r] * inv);
    }
}

extern "C" void kernel_launch(void* const* d_in, const int* in_sizes, int n_in,
                              void* d_out, int out_size, void* d_ws, size_t ws_size,
                              hipStream_t stream) {
    const float* x  = (const float*)d_in[0];
    const float* wq = (const float*)d_in[1];
    const float* bq = (const float*)d_in[2];
    const float* wk = (const float*)d_in[3];
    const float* bk = (const float*)d_in[4];
    const float* wv = (const float*)d_in[5];
    const float* bv = (const float*)d_in[6];
    const float* wo = (const float*)d_in[7];
    const float* bo = (const float*)d_in[8];
    float* out = (float*)d_out;

    ushort_t* ws  = (ushort_t*)d_ws;
    ushort_t* xb  = ws + OFF_XB;
    ushort_t* wb  = ws + OFF_WB;
    ushort_t* wob = ws + OFF_WOB;
    ushort_t* qkv = ws + OFF_QKV;
    ushort_t* Qb  = qkv;
    ushort_t* Kb  = qkv + (size_t)4 * 1024 * 1024;
    ushort_t* Vb  = qkv + (size_t)8 * 1024 * 1024;
    ushort_t* Ob  = ws + OFF_OB;

    convert5<<<dim3(1024, 5, 1), 256, 0, stream>>>(x, wq, wk, wv, wo, xb, wb, wob);
    gemm_nt<0><<<dim3(32, 8, 3), 256, 0, stream>>>(xb, wb, bq, bk, bv, qkv, nullptr);
    attn<<<dim3(32, 16, 2), 256, 0, stream>>>(Qb, Kb, Vb, Ob);
    gemm_nt<1><<<dim3(32, 8, 1), 256, 0, stream>>>(Ob, wob, bo, nullptr, nullptr, nullptr, out);
}

// Round 3
// 158.537 us; speedup vs baseline: 1.3718x; 1.3718x over previous
//
#include <hip/hip_runtime.h>
#include <hip/hip_bf16.h>
#include <math.h>

#define DEV __device__ __forceinline__

typedef float f32x4 __attribute__((ext_vector_type(4)));
typedef __bf16 b16x8 __attribute__((ext_vector_type(8)));
typedef unsigned short ushort_t;
typedef ushort_t u16x8 __attribute__((ext_vector_type(8)));

// ---- constants for this problem ----
#define BATCH 2
#define SEQ 2048
#define DMODEL 1024
#define NHEAD 16
#define HDIM 64
#define MROWS (BATCH * SEQ)          // 4096
#define LOG2E 1.44269504088896f

// ws layout (in ushort elements)
#define OFF_XB   ((size_t)0)                       // [4096,1024]
#define OFF_WB   ((size_t)4 * 1024 * 1024)         // [3][1024,1024] wq,wk,wv
#define OFF_WOB  ((size_t)7 * 1024 * 1024)         // [1024,1024]
#define OFF_QKV  ((size_t)8 * 1024 * 1024)         // Q,K: [2,16,2048,64]; V^T: [2,16,64,2048]
#define OFF_OB   ((size_t)20 * 1024 * 1024)        // [2,2048,16,64] == [4096,1024]

DEV ushort_t f2bf(float f) {
    union { float f; unsigned u; } v; v.f = f;
    unsigned r = v.u + 0x7fffu + ((v.u >> 16) & 1u);
    return (ushort_t)(r >> 16);
}

DEV unsigned cvt_pk_bf16(float lo, float hi) {
    unsigned r;
    asm("v_cvt_pk_bf16_f32 %0, %1, %2" : "=v"(r) : "v"(lo), "v"(hi));
    return r;
}

DEV f32x4 mfma16(u16x8 a, u16x8 b, f32x4 c) {
    return __builtin_amdgcn_mfma_f32_16x16x32_bf16(
        __builtin_bit_cast(b16x8, a), __builtin_bit_cast(b16x8, b), c, 0, 0, 0);
}

DEV void gload_lds16(const ushort_t* g, ushort_t* l) {
    __builtin_amdgcn_global_load_lds(
        (const __attribute__((address_space(1))) unsigned int*)g,
        (__attribute__((address_space(3))) unsigned int*)l, 16, 0, 0);
}

// ---------------- convert f32 -> bf16 ----------------
__global__ __launch_bounds__(256) void convert5(
    const float* __restrict__ x, const float* __restrict__ wq,
    const float* __restrict__ wk, const float* __restrict__ wv,
    const float* __restrict__ wo,
    ushort_t* __restrict__ xb, ushort_t* __restrict__ wb, ushort_t* __restrict__ wob)
{
    const int ai = blockIdx.y;
    const float* src; ushort_t* dst; int n;
    if (ai == 0)      { src = x;  dst = xb;                 n = MROWS * DMODEL; }
    else if (ai == 1) { src = wq; dst = wb;                 n = DMODEL * DMODEL; }
    else if (ai == 2) { src = wk; dst = wb + 1024 * 1024;   n = DMODEL * DMODEL; }
    else if (ai == 3) { src = wv; dst = wb + 2 * 1024 * 1024; n = DMODEL * DMODEL; }
    else              { src = wo; dst = wob;                n = DMODEL * DMODEL; }
    int idx = (blockIdx.x * 256 + threadIdx.x) * 4;
    int stride = gridDim.x * 256 * 4;
    for (int i = idx; i < n; i += stride) {
        float4 f = *(const float4*)(src + i);
        ushort4 u;
        u.x = f2bf(f.x); u.y = f2bf(f.y); u.z = f2bf(f.z); u.w = f2bf(f.w);
        *(ushort4*)(dst + i) = u;
    }
}

// ---------------- NT GEMM: Y[m,n] = sum_k A[m,k] * W[n,k] (+bias) ----------------
// MODE 0: QKV projection.  mat 0 (Q): bf16 [B,H,S,Hd], scaled by log2e/8.
//                          mat 1 (K): bf16 [B,H,S,Hd].
//                          mat 2 (V): bf16 [B,H,Hd,S]  (pre-transposed).
// MODE 1: output projection -> f32 d_out [4096,1024] + bias.
template<int MODE>
__global__ __launch_bounds__(256) void gemm_nt(
    const ushort_t* __restrict__ A,   // [4096,1024]
    const ushort_t* __restrict__ W,   // MODE0: [3][1024,1024]  MODE1: [1024,1024]
    const float* __restrict__ b0, const float* __restrict__ b1, const float* __restrict__ b2,
    ushort_t* __restrict__ obf,       // MODE0 dest base
    float* __restrict__ of32)         // MODE1 dest
{
    __shared__ __attribute__((aligned(16))) ushort_t ldsA[128 * 32];
    __shared__ __attribute__((aligned(16))) ushort_t ldsB[128 * 32];

    const int t = threadIdx.x;
    const int m0 = blockIdx.x * 128;
    const int n0 = blockIdx.y * 128;
    const int mat = blockIdx.z;
    const ushort_t* Wm = W + (size_t)mat * (1024 * 1024);
    const float* bias = (mat == 0) ? b0 : (mat == 1 ? b1 : b2);

    const int lane = t & 63, wave = t >> 6;
    const int wr = (wave >> 1) * 64, wc = (wave & 1) * 64;
    const int lr = lane & 15, lk = (lane >> 4) * 8;

    f32x4 acc[4][4] = {};

    for (int k0 = 0; k0 < DMODEL; k0 += 32) {
#pragma unroll
        for (int i = 0; i < 2; ++i) {
            int e = (i * 256 + t) * 8;
            int row = e >> 5, col = e & 31;
            gload_lds16(A  + (size_t)(m0 + row) * DMODEL + k0 + col, &ldsA[e]);
            gload_lds16(Wm + (size_t)(n0 + row) * DMODEL + k0 + col, &ldsB[e]);
        }
        __syncthreads();
        u16x8 av[4], bv[4];
#pragma unroll
        for (int i = 0; i < 4; ++i) av[i] = *(const u16x8*)&ldsA[(wr + i * 16 + lr) * 32 + lk];
#pragma unroll
        for (int i = 0; i < 4; ++i) bv[i] = *(const u16x8*)&ldsB[(wc + i * 16 + lr) * 32 + lk];
#pragma unroll
        for (int m = 0; m < 4; ++m)
#pragma unroll
            for (int n = 0; n < 4; ++n)
                acc[m][n] = mfma16(av[m], bv[n], acc[m][n]);
        __syncthreads();
    }

    const int lgr = (lane >> 4) * 4;
    if (MODE == 0) {
        ushort_t* dst = obf + (size_t)mat * ((size_t)MROWS * DMODEL);
        if (mat < 2) {
            // Q (scaled by log2e/8 for base-2 softmax) / K: [B,H,S,Hd]
            const float qscale = (mat == 0) ? (0.125f * LOG2E) : 1.0f;
#pragma unroll
            for (int m = 0; m < 4; ++m) {
                int row = m0 + wr + m * 16 + lgr;
#pragma unroll
                for (int n = 0; n < 4; ++n) {
                    int col = n0 + wc + n * 16 + lr;
                    float bcol = bias[col];
                    int h = col >> 6, hd = col & 63;
#pragma unroll
                    for (int r = 0; r < 4; ++r) {
                        int rr = row + r;
                        int bb = rr >> 11, s = rr & 2047;
                        float v = (acc[m][n][r] + bcol) * qscale;
                        dst[(((size_t)bb * NHEAD + h) * SEQ + s) * HDIM + hd] = f2bf(v);
                    }
                }
            }
        } else {
            // V transposed: [B,H,Hd,S]; pack 4 consecutive s into one 8B store.
#pragma unroll
            for (int m = 0; m < 4; ++m) {
                int row = m0 + wr + m * 16 + lgr;   // multiple of 4
                int bb = row >> 11, s = row & 2047;
#pragma unroll
                for (int n = 0; n < 4; ++n) {
                    int col = n0 + wc + n * 16 + lr;
                    float bcol = bias[col];
                    int h = col >> 6, hd = col & 63;
                    ushort4 pk;
                    pk.x = f2bf(acc[m][n][0] + bcol);
                    pk.y = f2bf(acc[m][n][1] + bcol);
                    pk.z = f2bf(acc[m][n][2] + bcol);
                    pk.w = f2bf(acc[m][n][3] + bcol);
                    *(ushort4*)&dst[(((size_t)bb * NHEAD + h) * HDIM + hd) * SEQ + s] = pk;
                }
            }
        }
    } else {
#pragma unroll
        for (int m = 0; m < 4; ++m) {
            int row = m0 + wr + m * 16 + lgr;
#pragma unroll
            for (int n = 0; n < 4; ++n) {
                int col = n0 + wc + n * 16 + lr;
                float bcol = b0[col];
#pragma unroll
                for (int r = 0; r < 4; ++r)
                    of32[(size_t)(row + r) * DMODEL + col] = acc[m][n][r] + bcol;
            }
        }
    }
}

// ---------------- flash attention (swapped QK^T, lane-local softmax) ----------------
// 1D grid of 1024 blocks, XCD-swizzled. 4 waves, each owns 16 q-rows.
// Q pre-scaled by log2e/sqrt(Hd); softmax in base-2 domain.
__global__ __launch_bounds__(256) void attn(
    const ushort_t* __restrict__ Q, const ushort_t* __restrict__ K,
    const ushort_t* __restrict__ Vt, ushort_t* __restrict__ O)
{
    __shared__ __attribute__((aligned(16))) ushort_t kt[64 * 72];      // K[t][d], stride 72
    __shared__ __attribute__((aligned(16))) ushort_t vt[64 * 72];      // V^T[d][t], stride 72
    __shared__ __attribute__((aligned(16))) ushort_t pt[4][16 * 72];   // per-wave P[q][t]

    const int t = threadIdx.x, lane = t & 63, wave = t >> 6;
    // bijective XCD swizzle: 1024 blocks = 8 XCDs x 128 consecutive
    const int id = blockIdx.x;
    const int swz = (id & 7) * 128 + (id >> 3);
    const int q0 = (swz & 31) * 64;
    const int h = (swz >> 5) & 15, b = swz >> 9;

    const size_t base = ((size_t)(b * NHEAD + h)) * (SEQ * HDIM);
    const ushort_t* Qh = Q + base;
    const ushort_t* Kh = K + base;
    const ushort_t* Vh = Vt + base;   // [Hd][S] tile rows

    const int lr = lane & 15, lg = lane >> 4, lk = lg * 8;

    // Q fragment (B-operand): Q[q=lr][d=lk+j], two K-slices
    u16x8 qf[2];
    {
        const ushort_t* qrow = Qh + (size_t)(q0 + wave * 16 + lr) * HDIM + lk;
        qf[0] = *(const u16x8*)(qrow);
        qf[1] = *(const u16x8*)(qrow + 32);
    }

    f32x4 oacc[4] = {};
    float m_run = -1e30f, l_run = 0.f;

    const int srow = t >> 2;           // staging row 0..63
    const int sc0 = (t & 3) * 16;      // staging col base
    ushort_t* ptw = pt[wave];

    for (int t0 = 0; t0 < SEQ; t0 += 64) {
        // ---- stage K rows (contiguous) and V^T rows (stride SEQ), vectorized ----
        {
            const ushort_t* kr = Kh + (size_t)(t0 + srow) * HDIM + sc0;
            u16x8 k0 = *(const u16x8*)kr;
            u16x8 k1 = *(const u16x8*)(kr + 8);
            const ushort_t* vr = Vh + (size_t)srow * SEQ + t0 + sc0;
            u16x8 v0 = *(const u16x8*)vr;
            u16x8 v1 = *(const u16x8*)(vr + 8);
            *(u16x8*)&kt[srow * 72 + sc0]     = k0;
            *(u16x8*)&kt[srow * 72 + sc0 + 8] = k1;
            *(u16x8*)&vt[srow * 72 + sc0]     = v0;
            *(u16x8*)&vt[srow * 72 + sc0 + 8] = v1;
        }
        __syncthreads();

        // ---- S^T = K Q^T : lane holds S[q=lr][t = n*16 + lg*4 + r] ----
        f32x4 s4[4] = {};
#pragma unroll
        for (int n = 0; n < 4; ++n) {
#pragma unroll
            for (int kk = 0; kk < 2; ++kk) {
                u16x8 kf = *(const u16x8*)&kt[(n * 16 + lr) * 72 + kk * 32 + lk];
                s4[n] = mfma16(kf, qf[kk], s4[n]);
            }
        }

        // ---- lane-local softmax over 16 values (one q-row per lane) ----
        float tmax = s4[0][0];
#pragma unroll
        for (int n = 0; n < 4; ++n)
#pragma unroll
            for (int r = 0; r < 4; ++r)
                tmax = fmaxf(tmax, s4[n][r]);
        tmax = fmaxf(tmax, __shfl_xor(tmax, 16));
        tmax = fmaxf(tmax, __shfl_xor(tmax, 32));

        float mnew = fmaxf(m_run, tmax);
        float alpha = __builtin_amdgcn_exp2f(m_run - mnew);
        m_run = mnew;

        float p[4][4];
        float psum = 0.f;
#pragma unroll
        for (int n = 0; n < 4; ++n)
#pragma unroll
            for (int r = 0; r < 4; ++r) {
                p[n][r] = __builtin_amdgcn_exp2f(s4[n][r] - mnew);
                psum += p[n][r];
            }
        psum += __shfl_xor(psum, 16);
        psum += __shfl_xor(psum, 32);
        l_run = l_run * alpha + psum;

        // ---- pack P to bf16, one ds_write_b64 per n-tile: P[q=lr][t] ----
#pragma unroll
        for (int n = 0; n < 4; ++n) {
            uint2 w;
            w.x = cvt_pk_bf16(p[n][0], p[n][1]);
            w.y = cvt_pk_bf16(p[n][2], p[n][3]);
            *(uint2*)&ptw[lr * 72 + n * 16 + lg * 4] = w;
        }

        // ---- rescale O accumulator (alpha broadcast from row-owner lanes) ----
        float a0 = __shfl(alpha, lg * 4 + 0, 16);
        float a1 = __shfl(alpha, lg * 4 + 1, 16);
        float a2 = __shfl(alpha, lg * 4 + 2, 16);
        float a3 = __shfl(alpha, lg * 4 + 3, 16);
#pragma unroll
        for (int n = 0; n < 4; ++n) {
            oacc[n][0] *= a0; oacc[n][1] *= a1;
            oacc[n][2] *= a2; oacc[n][3] *= a3;
        }

        // ---- O += P V : A = P[q][t] (wave-local LDS), B = V[t][d] from V^T tile ----
        u16x8 pa0 = *(const u16x8*)&ptw[lr * 72 + 0 * 32 + lk];
        u16x8 pa1 = *(const u16x8*)&ptw[lr * 72 + 1 * 32 + lk];
#pragma unroll
        for (int n = 0; n < 4; ++n) {
            u16x8 vf0 = *(const u16x8*)&vt[(n * 16 + lr) * 72 + 0 * 32 + lk];
            u16x8 vf1 = *(const u16x8*)&vt[(n * 16 + lr) * 72 + 1 * 32 + lk];
            oacc[n] = mfma16(pa0, vf0, oacc[n]);
            oacc[n] = mfma16(pa1, vf1, oacc[n]);
        }
        __syncthreads();   // before next tile overwrites kt/vt
    }

    // ---- epilogue: O[b, s, h*64+d] bf16; l broadcast from row-owner lanes ----
    float linv = 1.0f / l_run;
#pragma unroll
    for (int r = 0; r < 4; ++r) {
        float li = __shfl(linv, lg * 4 + r, 16);
        int sg = q0 + wave * 16 + lg * 4 + r;
        size_t obase = ((size_t)(b * SEQ + sg)) * DMODEL + h * HDIM;
#pragma unroll
        for (int n = 0; n < 4; ++n)
            O[obase + n * 16 + lr] = f2bf(oacc[n][r] * li);
    }
}

extern "C" void kernel_launch(void* const* d_in, const int* in_sizes, int n_in,
                              void* d_out, int out_size, void* d_ws, size_t ws_size,
                              hipStream_t stream) {
    const float* x  = (const float*)d_in[0];
    const float* wq = (const float*)d_in[1];
    const float* bq = (const float*)d_in[2];
    const float* wk = (const float*)d_in[3];
    const float* bk = (const float*)d_in[4];
    const float* wv = (const float*)d_in[5];
    const float* bv = (const float*)d_in[6];
    const float* wo = (const float*)d_in[7];
    const float* bo = (const float*)d_in[8];
    float* out = (float*)d_out;

    ushort_t* ws  = (ushort_t*)d_ws;
    ushort_t* xb  = ws + OFF_XB;
    ushort_t* wb  = ws + OFF_WB;
    ushort_t* wob = ws + OFF_WOB;
    ushort_t* qkv = ws + OFF_QKV;
    ushort_t* Qb  = qkv;
    ushort_t* Kb  = qkv + (size_t)4 * 1024 * 1024;
    ushort_t* Vb  = qkv + (size_t)8 * 1024 * 1024;   // [B,H,Hd,S]
    ushort_t* Ob  = ws + OFF_OB;

    convert5<<<dim3(1024, 5, 1), 256, 0, stream>>>(x, wq, wk, wv, wo, xb, wb, wob);
    gemm_nt<0><<<dim3(32, 8, 3), 256, 0, stream>>>(xb, wb, bq, bk, bv, qkv, nullptr);
    attn<<<dim3(1024, 1, 1), 256, 0, stream>>>(Qb, Kb, Vb, Ob);
    gemm_nt<1><<<dim3(32, 8, 1), 256, 0, stream>>>(Ob, wob, bo, nullptr, nullptr, nullptr, out);
}

// Round 4
// 140.436 us; speedup vs baseline: 1.5486x; 1.1289x over previous
//
#include <hip/hip_runtime.h>
#include <hip/hip_bf16.h>
#include <math.h>

#define DEV __device__ __forceinline__

typedef float f32x4 __attribute__((ext_vector_type(4)));
typedef float f32x16 __attribute__((ext_vector_type(16)));
typedef __bf16 b16x8 __attribute__((ext_vector_type(8)));
typedef unsigned short ushort_t;
typedef ushort_t u16x8 __attribute__((ext_vector_type(8)));

// ---- constants for this problem ----
#define BATCH 2
#define SEQ 2048
#define DMODEL 1024
#define NHEAD 16
#define HDIM 64
#define MROWS (BATCH * SEQ)          // 4096
#define LOG2E 1.44269504088896f

// ws layout (in ushort elements)
#define OFF_XB   ((size_t)0)                       // [4096,1024]
#define OFF_WB   ((size_t)4 * 1024 * 1024)         // [3][1024,1024] wq,wk,wv
#define OFF_WOB  ((size_t)7 * 1024 * 1024)         // [1024,1024]
#define OFF_QKV  ((size_t)8 * 1024 * 1024)         // Q,K: [2,16,2048,64]; V^T: [2,16,64,2048]
#define OFF_OB   ((size_t)20 * 1024 * 1024)        // [2,2048,16,64] == [4096,1024]

DEV ushort_t f2bf(float f) {
    union { float f; unsigned u; } v; v.f = f;
    unsigned r = v.u + 0x7fffu + ((v.u >> 16) & 1u);
    return (ushort_t)(r >> 16);
}

DEV unsigned cvt_pk_bf16(float lo, float hi) {
    unsigned r;
    asm("v_cvt_pk_bf16_f32 %0, %1, %2" : "=v"(r) : "v"(lo), "v"(hi));
    return r;
}

DEV f32x4 mfma16(u16x8 a, u16x8 b, f32x4 c) {
    return __builtin_amdgcn_mfma_f32_16x16x32_bf16(
        __builtin_bit_cast(b16x8, a), __builtin_bit_cast(b16x8, b), c, 0, 0, 0);
}

DEV f32x16 mfma32(u16x8 a, u16x8 b, f32x16 c) {
    return __builtin_amdgcn_mfma_f32_32x32x16_bf16(
        __builtin_bit_cast(b16x8, a), __builtin_bit_cast(b16x8, b), c, 0, 0, 0);
}

DEV void gload_lds16(const ushort_t* g, ushort_t* l) {
    __builtin_amdgcn_global_load_lds(
        (const __attribute__((address_space(1))) unsigned int*)g,
        (__attribute__((address_space(3))) unsigned int*)l, 16, 0, 0);
}

// ---------------- convert f32 -> bf16 ----------------
__global__ __launch_bounds__(256) void convert5(
    const float* __restrict__ x, const float* __restrict__ wq,
    const float* __restrict__ wk, const float* __restrict__ wv,
    const float* __restrict__ wo,
    ushort_t* __restrict__ xb, ushort_t* __restrict__ wb, ushort_t* __restrict__ wob)
{
    const int ai = blockIdx.y;
    const float* src; ushort_t* dst; int n;
    if (ai == 0)      { src = x;  dst = xb;                 n = MROWS * DMODEL; }
    else if (ai == 1) { src = wq; dst = wb;                 n = DMODEL * DMODEL; }
    else if (ai == 2) { src = wk; dst = wb + 1024 * 1024;   n = DMODEL * DMODEL; }
    else if (ai == 3) { src = wv; dst = wb + 2 * 1024 * 1024; n = DMODEL * DMODEL; }
    else              { src = wo; dst = wob;                n = DMODEL * DMODEL; }
    int idx = (blockIdx.x * 256 + threadIdx.x) * 4;
    int stride = gridDim.x * 256 * 4;
    for (int i = idx; i < n; i += stride) {
        float4 f = *(const float4*)(src + i);
        ushort4 u;
        u.x = f2bf(f.x); u.y = f2bf(f.y); u.z = f2bf(f.z); u.w = f2bf(f.w);
        *(ushort4*)(dst + i) = u;
    }
}

// ---------------- NT GEMM: Y[m,n] = sum_k A[m,k] * W[n,k] (+bias) ----------------
template<int MODE>
__global__ __launch_bounds__(256) void gemm_nt(
    const ushort_t* __restrict__ A,   // [4096,1024]
    const ushort_t* __restrict__ W,   // MODE0: [3][1024,1024]  MODE1: [1024,1024]
    const float* __restrict__ b0, const float* __restrict__ b1, const float* __restrict__ b2,
    ushort_t* __restrict__ obf,       // MODE0 dest base
    float* __restrict__ of32)         // MODE1 dest
{
    __shared__ __attribute__((aligned(16))) ushort_t ldsA[128 * 32];
    __shared__ __attribute__((aligned(16))) ushort_t ldsB[128 * 32];

    const int t = threadIdx.x;
    const int m0 = blockIdx.x * 128;
    const int n0 = blockIdx.y * 128;
    const int mat = blockIdx.z;
    const ushort_t* Wm = W + (size_t)mat * (1024 * 1024);
    const float* bias = (mat == 0) ? b0 : (mat == 1 ? b1 : b2);

    const int lane = t & 63, wave = t >> 6;
    const int wr = (wave >> 1) * 64, wc = (wave & 1) * 64;
    const int lr = lane & 15, lk = (lane >> 4) * 8;

    f32x4 acc[4][4] = {};

    for (int k0 = 0; k0 < DMODEL; k0 += 32) {
#pragma unroll
        for (int i = 0; i < 2; ++i) {
            int e = (i * 256 + t) * 8;
            int row = e >> 5, col = e & 31;
            gload_lds16(A  + (size_t)(m0 + row) * DMODEL + k0 + col, &ldsA[e]);
            gload_lds16(Wm + (size_t)(n0 + row) * DMODEL + k0 + col, &ldsB[e]);
        }
        __syncthreads();
        u16x8 av[4], bv[4];
#pragma unroll
        for (int i = 0; i < 4; ++i) av[i] = *(const u16x8*)&ldsA[(wr + i * 16 + lr) * 32 + lk];
#pragma unroll
        for (int i = 0; i < 4; ++i) bv[i] = *(const u16x8*)&ldsB[(wc + i * 16 + lr) * 32 + lk];
#pragma unroll
        for (int m = 0; m < 4; ++m)
#pragma unroll
            for (int n = 0; n < 4; ++n)
                acc[m][n] = mfma16(av[m], bv[n], acc[m][n]);
        __syncthreads();
    }

    const int lgr = (lane >> 4) * 4;
    if (MODE == 0) {
        ushort_t* dst = obf + (size_t)mat * ((size_t)MROWS * DMODEL);
        if (mat < 2) {
            const float qscale = (mat == 0) ? (0.125f * LOG2E) : 1.0f;
#pragma unroll
            for (int m = 0; m < 4; ++m) {
                int row = m0 + wr + m * 16 + lgr;
#pragma unroll
                for (int n = 0; n < 4; ++n) {
                    int col = n0 + wc + n * 16 + lr;
                    float bcol = bias[col];
                    int h = col >> 6, hd = col & 63;
#pragma unroll
                    for (int r = 0; r < 4; ++r) {
                        int rr = row + r;
                        int bb = rr >> 11, s = rr & 2047;
                        float v = (acc[m][n][r] + bcol) * qscale;
                        dst[(((size_t)bb * NHEAD + h) * SEQ + s) * HDIM + hd] = f2bf(v);
                    }
                }
            }
        } else {
            // V transposed: [B,H,Hd,S]; pack 4 consecutive s into one 8B store.
#pragma unroll
            for (int m = 0; m < 4; ++m) {
                int row = m0 + wr + m * 16 + lgr;   // multiple of 4
                int bb = row >> 11, s = row & 2047;
#pragma unroll
                for (int n = 0; n < 4; ++n) {
                    int col = n0 + wc + n * 16 + lr;
                    float bcol = bias[col];
                    int h = col >> 6, hd = col & 63;
                    ushort4 pk;
                    pk.x = f2bf(acc[m][n][0] + bcol);
                    pk.y = f2bf(acc[m][n][1] + bcol);
                    pk.z = f2bf(acc[m][n][2] + bcol);
                    pk.w = f2bf(acc[m][n][3] + bcol);
                    *(ushort4*)&dst[(((size_t)bb * NHEAD + h) * HDIM + hd) * SEQ + s] = pk;
                }
            }
        }
    } else {
#pragma unroll
        for (int m = 0; m < 4; ++m) {
            int row = m0 + wr + m * 16 + lgr;
#pragma unroll
            for (int n = 0; n < 4; ++n) {
                int col = n0 + wc + n * 16 + lr;
                float bcol = b0[col];
#pragma unroll
                for (int r = 0; r < 4; ++r)
                    of32[(size_t)(row + r) * DMODEL + col] = acc[m][n][r] + bcol;
            }
        }
    }
}

// ---------------- flash attention: 32x32 MFMA, QBLK=32/wave, 4 waves ----------------
// Swapped QK^T: S^T[t][q] = mfma32(A=K[t][d], B=Q^T[d][q]), C seeded with -m_run.
// C-layout (verified): col = lane&31, row = (reg&3) + 8*(reg>>2) + 4*(lane>>5).
// Q pre-scaled by log2e/8; softmax in base-2 domain, m_run init 0 (shift-invariant).
__global__ __launch_bounds__(256, 2) void attn(
    const ushort_t* __restrict__ Q, const ushort_t* __restrict__ K,
    const ushort_t* __restrict__ Vt, ushort_t* __restrict__ O)
{
    __shared__ __attribute__((aligned(16))) ushort_t kt[64 * 72];        // K[t][d]
    __shared__ __attribute__((aligned(16))) ushort_t vt[64 * 72];        // V^T[d][t]
    __shared__ __attribute__((aligned(16))) ushort_t pbuf[4][32 * 72];   // per-wave P[q][t]
    __shared__ float abuf[4][32];                                        // per-wave q-broadcast

    const int t = threadIdx.x, lane = t & 63, wave = t >> 6;
    const int lq = lane & 31, hi = lane >> 5;

    // bijective XCD swizzle: 512 blocks = 8 XCDs x 64; same (b,h) lands on one XCD
    const int id = blockIdx.x;
    const int swz = (id & 7) * 64 + (id >> 3);
    const int q0 = (swz & 15) * 128;
    const int h = (swz >> 4) & 15, b = swz >> 8;

    const size_t base = ((size_t)(b * NHEAD + h)) * (SEQ * HDIM);
    const ushort_t* Qh = Q + base;
    const ushort_t* Kh = K + base;
    const ushort_t* Vh = Vt + base;   // [Hd][S]

    const int q0w = q0 + wave * 32;

    // Q B-fragments: lane provides Q[q=lq][d = 16*step + 8*hi + j]
    u16x8 qf[4];
#pragma unroll
    for (int step = 0; step < 4; ++step)
        qf[step] = *(const u16x8*)(Qh + (size_t)(q0w + lq) * HDIM + step * 16 + hi * 8);

    f32x16 o0 = {}, o1 = {};          // O d-tiles: col d = dt*32+lq, row q per C-layout
    float m_run = 0.f, l_run = 0.f;

    const int srow = t >> 2;           // staging row 0..63
    const int sc0 = (t & 3) * 16;      // staging col base
    ushort_t* ptw = pbuf[wave];

    for (int t0 = 0; t0 < SEQ; t0 += 64) {
        // ---- stage K[t][d] and V^T[d][t], vectorized 32B/thread each ----
        {
            const ushort_t* kr = Kh + (size_t)(t0 + srow) * HDIM + sc0;
            u16x8 k0 = *(const u16x8*)kr;
            u16x8 k1 = *(const u16x8*)(kr + 8);
            const ushort_t* vr = Vh + (size_t)srow * SEQ + t0 + sc0;
            u16x8 v0 = *(const u16x8*)vr;
            u16x8 v1 = *(const u16x8*)(vr + 8);
            *(u16x8*)&kt[srow * 72 + sc0]     = k0;
            *(u16x8*)&kt[srow * 72 + sc0 + 8] = k1;
            *(u16x8*)&vt[srow * 72 + sc0]     = v0;
            *(u16x8*)&vt[srow * 72 + sc0 + 8] = v1;
        }
        __syncthreads();

        // ---- S^T = K Q^T, C seeded with -m_run ----
        f32x16 s0, s1;
#pragma unroll
        for (int r = 0; r < 16; ++r) { s0[r] = -m_run; s1[r] = -m_run; }
#pragma unroll
        for (int step = 0; step < 4; ++step) {
            u16x8 kf0 = *(const u16x8*)&kt[(lq)      * 72 + step * 16 + hi * 8];
            u16x8 kf1 = *(const u16x8*)&kt[(32 + lq) * 72 + step * 16 + hi * 8];
            s0 = mfma32(kf0, qf[step], s0);
            s1 = mfma32(kf1, qf[step], s1);
        }

        // ---- row max (lane-local 31 + cross-half) ----
        float pm = fmaxf(s0[0], s1[0]);
#pragma unroll
        for (int r = 1; r < 16; ++r) pm = fmaxf(pm, fmaxf(s0[r], s1[r]));
        pm = fmaxf(pm, __shfl_xor(pm, 32));

        // ---- exp (defer-max: rescale only if any row grew past THR=8) ----
        f32x16 p0, p1;
        if (__any(pm > 8.0f)) {
            float dlt = fmaxf(pm, 0.f);
            float alpha = __builtin_amdgcn_exp2f(-dlt);
            m_run += dlt;
#pragma unroll
            for (int r = 0; r < 16; ++r) {
                p0[r] = __builtin_amdgcn_exp2f(s0[r] - dlt);
                p1[r] = __builtin_amdgcn_exp2f(s1[r] - dlt);
            }
            if (lane < 32) abuf[wave][lq] = alpha;   // in-wave DS ordering
#pragma unroll
            for (int g = 0; g < 4; ++g) {
                f32x4 a4 = *(const f32x4*)&abuf[wave][g * 8 + hi * 4];
#pragma unroll
                for (int k = 0; k < 4; ++k) {
                    o0[g * 4 + k] *= a4[k];
                    o1[g * 4 + k] *= a4[k];
                }
            }
            l_run *= alpha;
        } else {
#pragma unroll
            for (int r = 0; r < 16; ++r) {
                p0[r] = __builtin_amdgcn_exp2f(s0[r]);
                p1[r] = __builtin_amdgcn_exp2f(s1[r]);
            }
        }

        // ---- row sum ----
        float ps = p0[0] + p1[0];
#pragma unroll
        for (int r = 1; r < 16; ++r) ps += p0[r] + p1[r];
        ps += __shfl_xor(ps, 32);
        l_run += ps;

        // ---- pack P -> per-wave LDS [q][t32 = 8g + 4hi + (0..3)] ----
#pragma unroll
        for (int g = 0; g < 4; ++g) {
            uint2 w;
            w.x = cvt_pk_bf16(p0[g * 4 + 0], p0[g * 4 + 1]);
            w.y = cvt_pk_bf16(p0[g * 4 + 2], p0[g * 4 + 3]);
            *(uint2*)&ptw[lq * 72 + g * 8 + hi * 4] = w;
            uint2 w2;
            w2.x = cvt_pk_bf16(p1[g * 4 + 0], p1[g * 4 + 1]);
            w2.y = cvt_pk_bf16(p1[g * 4 + 2], p1[g * 4 + 3]);
            *(uint2*)&ptw[lq * 72 + 32 + g * 8 + hi * 4] = w2;
        }

        // ---- O += P V : A = P[q][t], B = V[t][d] from vt rows ----
#pragma unroll
        for (int s = 0; s < 4; ++s) {
            u16x8 pa  = *(const u16x8*)&ptw[lq * 72 + s * 16 + hi * 8];
            u16x8 vf0 = *(const u16x8*)&vt[(lq)      * 72 + s * 16 + hi * 8];
            u16x8 vf1 = *(const u16x8*)&vt[(32 + lq) * 72 + s * 16 + hi * 8];
            o0 = mfma32(pa, vf0, o0);
            o1 = mfma32(pa, vf1, o1);
        }
        __syncthreads();   // before next tile overwrites kt/vt
    }

    // ---- epilogue: redistribute 1/l to C-layout rows, store O[b,s,h*64+d] ----
    float linv = 1.0f / l_run;
    if (lane < 32) abuf[wave][lq] = linv;
#pragma unroll
    for (int g = 0; g < 4; ++g) {
        f32x4 l4 = *(const f32x4*)&abuf[wave][g * 8 + hi * 4];
#pragma unroll
        for (int k = 0; k < 4; ++k) {
            int r = g * 4 + k;
            int sg = q0w + g * 8 + hi * 4 + k;
            size_t obase = ((size_t)(b * SEQ + sg)) * DMODEL + h * HDIM;
            O[obase + lq]      = f2bf(o0[r] * l4[k]);
            O[obase + 32 + lq] = f2bf(o1[r] * l4[k]);
        }
    }
}

extern "C" void kernel_launch(void* const* d_in, const int* in_sizes, int n_in,
                              void* d_out, int out_size, void* d_ws, size_t ws_size,
                              hipStream_t stream) {
    const float* x  = (const float*)d_in[0];
    const float* wq = (const float*)d_in[1];
    const float* bq = (const float*)d_in[2];
    const float* wk = (const float*)d_in[3];
    const float* bk = (const float*)d_in[4];
    const float* wv = (const float*)d_in[5];
    const float* bv = (const float*)d_in[6];
    const float* wo = (const float*)d_in[7];
    const float* bo = (const float*)d_in[8];
    float* out = (float*)d_out;

    ushort_t* ws  = (ushort_t*)d_ws;
    ushort_t* xb  = ws + OFF_XB;
    ushort_t* wb  = ws + OFF_WB;
    ushort_t* wob = ws + OFF_WOB;
    ushort_t* qkv = ws + OFF_QKV;
    ushort_t* Qb  = qkv;
    ushort_t* Kb  = qkv + (size_t)4 * 1024 * 1024;
    ushort_t* Vb  = qkv + (size_t)8 * 1024 * 1024;   // [B,H,Hd,S]
    ushort_t* Ob  = ws + OFF_OB;

    convert5<<<dim3(1024, 5, 1), 256, 0, stream>>>(x, wq, wk, wv, wo, xb, wb, wob);
    gemm_nt<0><<<dim3(32, 8, 3), 256, 0, stream>>>(xb, wb, bq, bk, bv, qkv, nullptr);
    attn<<<dim3(512, 1, 1), 256, 0, stream>>>(Qb, Kb, Vb, Ob);
    gemm_nt<1><<<dim3(32, 8, 1), 256, 0, stream>>>(Ob, wob, bo, nullptr, nullptr, nullptr, out);
}